// Round 5
// baseline (238.183 us; speedup 1.0000x reference)
//
#include <hip/hip_runtime.h>
#include <math.h>

// Problem constants (MicroGPT)
constexpr int Bc  = 16;
constexpr int Tc  = 2048;
constexpr int Cc  = 16;
constexpr int Hc  = 2;
constexpr int HSc = 8;
constexpr int Lc  = 2;
constexpr int Vc  = 256;
constexpr int BT  = Bc * Tc;          // 32768 tokens
constexpr float EPSc = 1e-5f;

// Attention tiling: K-chunk split + 4 queries/thread
constexpr int KC  = 128;              // keys per chunk (LDS tile)
constexpr int NCH = Tc / KC;          // 16 chunks
constexpr int QB  = 1024;             // queries per block (256 thr x 4 ILP)
constexpr int NQB = Tc / QB;          // 2 query blocks per (b,h)

typedef float f2 __attribute__((ext_vector_type(2)));

__device__ inline float shx(float v, int m) { return __shfl_xor(v, m, 64); }

// ---------------------------------------------------------------------------
// LN helper: 16-wide layernorm entirely in registers
// ---------------------------------------------------------------------------
__device__ inline void layernorm16(const float* xr, float* h,
                                   const float* g, const float* b) {
  float m = 0.f;
#pragma unroll
  for (int c = 0; c < Cc; c++) m += xr[c];
  m *= (1.f / Cc);
  float var = 0.f;
#pragma unroll
  for (int c = 0; c < Cc; c++) { float d = xr[c] - m; var += d * d; }
  var *= (1.f / Cc);
  float rs = rsqrtf(var + EPSc);
#pragma unroll
  for (int c = 0; c < Cc; c++) h[c] = (xr[c] - m) * rs * g[c] + b[c];
}

// ---------------------------------------------------------------------------
// 4-lane-coop QKV: lane j computes s={2j,2j+1} of every (head, q/k/v) vector
// ---------------------------------------------------------------------------
__device__ inline void qkv_store_lane(const float* h, const float* swq,
                                      const float* swk, const float* swv,
                                      int bb, int tt, int j,
                                      float* __restrict__ q,
                                      float* __restrict__ k,
                                      float* __restrict__ v) {
#pragma unroll
  for (int hh = 0; hh < Hc; hh++) {
    float q0 = 0.f, q1 = 0.f, k0 = 0.f, k1 = 0.f, v0 = 0.f, v1 = 0.f;
#pragma unroll
    for (int c = 0; c < Cc; c++) {
      float hv = h[c];
      const float* wqp = swq + (hh * Cc + c) * HSc + 2 * j;
      const float* wkp = swk + (hh * Cc + c) * HSc + 2 * j;
      const float* wvp = swv + (hh * Cc + c) * HSc + 2 * j;
      q0 += hv * wqp[0]; q1 += hv * wqp[1];
      k0 += hv * wkp[0]; k1 += hv * wkp[1];
      v0 += hv * wvp[0]; v1 += hv * wvp[1];
    }
    long base = ((long)(bb * Hc + hh) * Tc + tt) * HSc;
    ((float2*)(q + base))[j] = make_float2(q0, q1);
    ((float2*)(k + base))[j] = make_float2(k0, k1);
    ((float2*)(v + base))[j] = make_float2(v0, v1);
  }
}

// ---------------------------------------------------------------------------
// K1) x = tok_emb[idx] + pos_emb ; h = LN1(x) ; q,k,v = h @ W  (layer 0)
//     4 lanes per token: 64 tokens per 256-thr block, 512 blocks.
// ---------------------------------------------------------------------------
__global__ __launch_bounds__(256, 4) void embed_ln_qkv_kernel(
    const int* __restrict__ idx, const float* __restrict__ tok,
    const float* __restrict__ pos,
    const float* __restrict__ wq, const float* __restrict__ wk,
    const float* __restrict__ wv,
    const float* __restrict__ g, const float* __restrict__ b,
    float* __restrict__ x, float* __restrict__ q, float* __restrict__ k,
    float* __restrict__ v) {
  __shared__ float swq[256], swk[256], swv[256], sg[Cc], sb[Cc];
  int tid = threadIdx.x;
  swq[tid] = wq[tid];
  swk[tid] = wk[tid];
  swv[tid] = wv[tid];
  if (tid < Cc) { sg[tid] = g[tid]; sb[tid] = b[tid]; }
  __syncthreads();

  int tk = blockIdx.x * 64 + (tid >> 2);
  int j  = tid & 3;
  int tt = tk & (Tc - 1);
  int bb = tk >> 11;
  int id = idx[tk];
  float xr[Cc];
  const float4* te = (const float4*)(tok + id * Cc);
  const float4* pe = (const float4*)(pos + tt * Cc);
#pragma unroll
  for (int i = 0; i < 4; i++) {
    float4 a = te[i], p = pe[i];
    xr[4*i] = a.x + p.x; xr[4*i+1] = a.y + p.y;
    xr[4*i+2] = a.z + p.z; xr[4*i+3] = a.w + p.w;
  }
  ((float4*)(x + (long)tk * Cc))[j] =
      make_float4(xr[4*j], xr[4*j+1], xr[4*j+2], xr[4*j+3]);
  float h[Cc];
  layernorm16(xr, h, sg, sb);
  qkv_store_lane(h, swq, swk, swv, bb, tt, j, q, k, v);
}

// ---------------------------------------------------------------------------
// K2) Causal flash attention, K-chunk split, 4 queries/thread, packed f32.
//     Writes UNNORMALIZED partials (acc[8], l) per (query, chunk).
//     No max subtraction (|score| << 1 -> exp safe; softmax shift-invariant).
//     launch_bounds(256,4): 128-VGPR budget -- qr+acc alone need 64 VGPRs;
//     the old 8-wave/EU default (64 VGPRs) caused inner-loop spills.
// ---------------------------------------------------------------------------
__global__ __launch_bounds__(256, 4) void attn_kernel(
    const float* __restrict__ q, const float* __restrict__ k,
    const float* __restrict__ v, float* __restrict__ pacc,
    float* __restrict__ pl) {
  int bh = blockIdx.x;            // 0..31
  int ch = blockIdx.y;            // 0..15
  int qb = blockIdx.z;            // 0..1
  int k0 = ch * KC;
  if (k0 >= (qb + 1) * QB) return;       // chunk entirely in causal future

  __shared__ float sk[KC * HSc], sv[KC * HSc];
  int tid = threadIdx.x;
  {
    const float4* ksrc = (const float4*)(k + ((long)bh * Tc + k0) * HSc);
    const float4* vsrc = (const float4*)(v + ((long)bh * Tc + k0) * HSc);
    ((float4*)sk)[tid] = ksrc[tid];      // KC*HSc/4 == 256 == blockDim
    ((float4*)sv)[tid] = vsrc[tid];
  }
  __syncthreads();

  const float pre = 0.35355339059327373f * 1.4426950408889634f;
  int q0 = qb * QB + tid;         // queries q0 + 256*i
  f2 qr[4][4];
  f2 acc[4][4];
  float l[4] = {0.f, 0.f, 0.f, 0.f};
  int kmax[4];
#pragma unroll
  for (int i = 0; i < 4; i++) {
    int qi = q0 + 256 * i;
    const f2* qp = (const f2*)(q + ((long)bh * Tc + qi) * HSc);
#pragma unroll
    for (int jj = 0; jj < 4; jj++) {
      qr[i][jj] = qp[jj] * pre;
      acc[i][jj] = {0.f, 0.f};
    }
    int km = qi + 1 - k0;
    kmax[i] = km < 0 ? 0 : (km > KC ? KC : km);
  }

  const f2* skp = (const f2*)sk;
  const f2* svp = (const f2*)sv;

#define ATTN_STEP(u, MASKED)                                              \
  {                                                                       \
    f2 k0v = skp[(u)*4+0], k1v = skp[(u)*4+1],                            \
       k2v = skp[(u)*4+2], k3v = skp[(u)*4+3];                            \
    f2 v0v = svp[(u)*4+0], v1v = svp[(u)*4+1],                            \
       v2v = svp[(u)*4+2], v3v = svp[(u)*4+3];                            \
    _Pragma("unroll")                                                     \
    for (int i = 0; i < 4; i++) {                                         \
      f2 d = qr[i][0] * k0v;                                              \
      d += qr[i][1] * k1v;                                                \
      d += qr[i][2] * k2v;                                                \
      d += qr[i][3] * k3v;                                                \
      float s = d.x + d.y;                                                \
      float p = __builtin_amdgcn_exp2f(s);                                \
      if (MASKED) p = ((u) < kmax[i]) ? p : 0.f;                          \
      l[i] += p;                                                          \
      acc[i][0] += p * v0v;                                               \
      acc[i][1] += p * v1v;                                               \
      acc[i][2] += p * v2v;                                               \
      acc[i][3] += p * v3v;                                               \
    }                                                                     \
  }

  bool full = (k0 + KC) <= qb * QB;   // all 4 queries see every key in chunk
  if (full) {
#pragma unroll 2
    for (int u = 0; u < KC; u++) ATTN_STEP(u, false)
  } else {
    int bound = kmax[3];
    for (int u = 0; u < bound; u++) ATTN_STEP(u, true)
  }
#undef ATTN_STEP

  long rec = (long)(bh * NCH + ch) * Tc;
#pragma unroll
  for (int i = 0; i < 4; i++) {
    if (kmax[i] > 0) {
      int qi = q0 + 256 * i;
      float4* pa = (float4*)(pacc + (rec + qi) * 8);
      pa[0] = make_float4(acc[i][0].x, acc[i][0].y, acc[i][1].x, acc[i][1].y);
      pa[1] = make_float4(acc[i][2].x, acc[i][2].y, acc[i][3].x, acc[i][3].y);
      pl[rec + qi] = l[i];
    }
  }
}

// ---------------------------------------------------------------------------
// 4-lane cooperative tail: reduce partials -> o ; x += o@wo^T ; x += MLP(LN2)
// Lane roles (j = lane&3):
//   A: head j&1, chunks (j>>1)::2   -> shfl_xor combine
//   B: proj outputs c = 4j..4j+3    -> shfl_xor replicate
//   C: MLP hidden units j*16..+15   -> shfl_xor combine
// LDS layouts: swo [16][17] padded, sw1 [64][17] padded, sw2 [16][64].
// xr: in = x row, out = final residual row (all lanes full).
// ---------------------------------------------------------------------------
__device__ inline void coop_tail(
    const float* __restrict__ pacc, const float* __restrict__ pl,
    const float* swo, const float* sw1, const float* sw2,
    const float* sg2, const float* sb2, int bb, int tt, int j, float* xr) {
  // --- A: attention partial reduce
  int hh  = j & 1;
  int bh  = bb * Hc + hh;
  int nch = tt / KC + 1;
  float o8[8] = {0,0,0,0,0,0,0,0};
  float l = 0.f;
#pragma unroll 2
  for (int ch = (j >> 1); ch < nch; ch += 2) {
    long rec = (long)(bh * NCH + ch) * Tc + tt;
    const float4* pa = (const float4*)(pacc + rec * 8);
    float4 a = pa[0], b = pa[1];
    o8[0]+=a.x; o8[1]+=a.y; o8[2]+=a.z; o8[3]+=a.w;
    o8[4]+=b.x; o8[5]+=b.y; o8[6]+=b.z; o8[7]+=b.w;
    l += pl[rec];
  }
#pragma unroll
  for (int s = 0; s < 8; s++) o8[s] += shx(o8[s], 2);
  l += shx(l, 2);
  float inv = 1.f / l;
  float own[8], oth[8];
#pragma unroll
  for (int s = 0; s < 8; s++) own[s] = o8[s] * inv;
#pragma unroll
  for (int s = 0; s < 8; s++) oth[s] = shx(own[s], 1);
  float orow[Cc];
#pragma unroll
  for (int s = 0; s < 8; s++) {
    orow[s]     = (hh == 0) ? own[s] : oth[s];
    orow[8 + s] = (hh == 0) ? oth[s] : own[s];
  }
  // --- B: proj, c = 4j..4j+3
  float xc[4];
#pragma unroll
  for (int qq = 0; qq < 4; qq++) {
    int c = 4 * j + qq;
    float acc = xr[c];
#pragma unroll
    for (int kk = 0; kk < Cc; kk++) acc += orow[kk] * swo[c * 17 + kk];
    xc[qq] = acc;
  }
  {
    float p[4];
#pragma unroll
    for (int qq = 0; qq < 4; qq++) p[qq] = shx(xc[qq], 1);
    bool lo = (j & 1) == 0;
    float a8[8], b8[8];
#pragma unroll
    for (int qq = 0; qq < 4; qq++) {
      a8[qq]     = lo ? xc[qq] : p[qq];
      a8[4 + qq] = lo ? p[qq] : xc[qq];
    }
#pragma unroll
    for (int s = 0; s < 8; s++) b8[s] = shx(a8[s], 2);
    bool lo2 = (j & 2) == 0;
#pragma unroll
    for (int s = 0; s < 8; s++) {
      xr[s]     = lo2 ? a8[s] : b8[s];
      xr[8 + s] = lo2 ? b8[s] : a8[s];
    }
  }
  // --- C: MLP, hidden units j*16..j*16+15
  float h[Cc];
  layernorm16(xr, h, sg2, sb2);
  float r[Cc];
#pragma unroll
  for (int c = 0; c < Cc; c++) r[c] = 0.f;
#pragma unroll
  for (int i = 0; i < 16; i++) {
    int jj = j * 16 + i;
    float acc = 0.f;
#pragma unroll
    for (int c = 0; c < Cc; c++) acc += h[c] * sw1[jj * 17 + c];
    acc = fmaxf(acc, 0.f);
#pragma unroll
    for (int c = 0; c < Cc; c++) r[c] += acc * sw2[c * 64 + jj];
  }
#pragma unroll
  for (int c = 0; c < Cc; c++) r[c] += shx(r[c], 1);
#pragma unroll
  for (int c = 0; c < Cc; c++) r[c] += shx(r[c], 2);
#pragma unroll
  for (int c = 0; c < Cc; c++) xr[c] += r[c];
}

// ---------------------------------------------------------------------------
// K3) layer-l epilogue + layer-(l+1) LN1+QKV  (4-lane coop, 512 blocks)
// ---------------------------------------------------------------------------
__global__ __launch_bounds__(256, 4) void red_mid_kernel(
    const float* __restrict__ pacc, const float* __restrict__ pl,
    const float* __restrict__ wo, const float* __restrict__ g2,
    const float* __restrict__ b2, const float* __restrict__ w1,
    const float* __restrict__ w2,
    const float* __restrict__ wq, const float* __restrict__ wk,
    const float* __restrict__ wv, const float* __restrict__ g1,
    const float* __restrict__ b1,
    float* __restrict__ x, float* __restrict__ q, float* __restrict__ k,
    float* __restrict__ v) {
  __shared__ float swo[16 * 17], sw1[64 * 17], sw2[1024];
  __shared__ float swq[256], swk[256], swv[256];
  __shared__ float sg2[Cc], sb2[Cc], sg1[Cc], sb1[Cc];
  int tid = threadIdx.x;
  swq[tid] = wq[tid]; swk[tid] = wk[tid]; swv[tid] = wv[tid];
  { int rr = tid >> 4, c = tid & 15; swo[rr * 17 + c] = wo[tid]; }
#pragma unroll
  for (int t = tid; t < 1024; t += 256) {
    int jj = t >> 4, c = t & 15;
    sw1[jj * 17 + c] = w1[t];
    sw2[t] = w2[t];
  }
  if (tid < Cc) {
    sg2[tid] = g2[tid]; sb2[tid] = b2[tid];
    sg1[tid] = g1[tid]; sb1[tid] = b1[tid];
  }
  __syncthreads();

  int tk = blockIdx.x * 64 + (tid >> 2);
  int j  = tid & 3;
  int bb = tk >> 11, tt = tk & (Tc - 1);
  float xr[Cc];
  const float4* xp = (const float4*)(x + (long)tk * Cc);
#pragma unroll
  for (int i = 0; i < 4; i++) {
    float4 a = xp[i];
    xr[4*i]=a.x; xr[4*i+1]=a.y; xr[4*i+2]=a.z; xr[4*i+3]=a.w;
  }
  coop_tail(pacc, pl, swo, sw1, sw2, sg2, sb2, bb, tt, j, xr);
  ((float4*)(x + (long)tk * Cc))[j] =
      make_float4(xr[4*j], xr[4*j+1], xr[4*j+2], xr[4*j+3]);
  float h[Cc];
  layernorm16(xr, h, sg1, sb1);
  qkv_store_lane(h, swq, swk, swv, bb, tt, j, q, k, v);
}

// ---------------------------------------------------------------------------
// K5) final-layer epilogue + LNf + tied lm_head  (4-lane coop + head phase)
// ---------------------------------------------------------------------------
__global__ __launch_bounds__(256, 4) void red_lnf_head_kernel(
    const float* __restrict__ pacc, const float* __restrict__ pl,
    const float* __restrict__ wo, const float* __restrict__ g2,
    const float* __restrict__ b2, const float* __restrict__ w1,
    const float* __restrict__ w2, const float* __restrict__ gf,
    const float* __restrict__ bf,
    const float* __restrict__ x, const float* __restrict__ tok,
    float* __restrict__ out) {
  __shared__ float swo[16 * 17], sw1[64 * 17], sw2[1024];
  __shared__ float sg2[Cc], sb2[Cc], sgf[Cc], sbf[Cc];
  __shared__ float sh[64 * Cc];
  int tid = threadIdx.x;
  { int rr = tid >> 4, c = tid & 15; swo[rr * 17 + c] = wo[tid]; }
#pragma unroll
  for (int t = tid; t < 1024; t += 256) {
    int jj = t >> 4, c = t & 15;
    sw1[jj * 17 + c] = w1[t];
    sw2[t] = w2[t];
  }
  if (tid < Cc) {
    sg2[tid] = g2[tid]; sb2[tid] = b2[tid];
    sgf[tid] = gf[tid]; sbf[tid] = bf[tid];
  }
  __syncthreads();

  int tk = blockIdx.x * 64 + (tid >> 2);
  int j  = tid & 3;
  int bb = tk >> 11, tt = tk & (Tc - 1);
  float xr[Cc];
  const float4* xp = (const float4*)(x + (long)tk * Cc);
#pragma unroll
  for (int i = 0; i < 4; i++) {
    float4 a = xp[i];
    xr[4*i]=a.x; xr[4*i+1]=a.y; xr[4*i+2]=a.z; xr[4*i+3]=a.w;
  }
  coop_tail(pacc, pl, swo, sw1, sw2, sg2, sb2, bb, tt, j, xr);
  float h[Cc];
  layernorm16(xr, h, sgf, sbf);
  ((float4*)(sh + (tid >> 2) * Cc))[j] =
      make_float4(h[4*j], h[4*j+1], h[4*j+2], h[4*j+3]);
  __syncthreads();

  // head phase: thread = vocab id, 64 tokens from LDS (broadcast reads)
  float4 e0, e1, e2, e3;
  {
    const float4* ep = (const float4*)(tok + tid * Cc);
    e0 = ep[0]; e1 = ep[1]; e2 = ep[2]; e3 = ep[3];
  }
  int row0 = blockIdx.x * 64;
#pragma unroll 4
  for (int t = 0; t < 64; t++) {
    const float4* hp = (const float4*)(sh + t * Cc);
    float4 h0 = hp[0], h1 = hp[1], h2 = hp[2], h3 = hp[3];
    float acc = h0.x*e0.x + h0.y*e0.y + h0.z*e0.z + h0.w*e0.w
              + h1.x*e1.x + h1.y*e1.y + h1.z*e1.z + h1.w*e1.w
              + h2.x*e2.x + h2.y*e2.y + h2.z*e2.z + h2.w*e2.w
              + h3.x*e3.x + h3.y*e3.y + h3.z*e3.z + h3.w*e3.w;
    out[(long)(row0 + t) * Vc + tid] = acc;
  }
}

// ---------------------------------------------------------------------------
// launcher
// ---------------------------------------------------------------------------
extern "C" void kernel_launch(void* const* d_in, const int* in_sizes, int n_in,
                              void* d_out, int out_size, void* d_ws,
                              size_t ws_size, hipStream_t stream) {
  const int*   idx  = (const int*)  d_in[0];
  const float* tok  = (const float*)d_in[1];
  const float* pos  = (const float*)d_in[2];
  const float* wq   = (const float*)d_in[3];
  const float* wk   = (const float*)d_in[4];
  const float* wv   = (const float*)d_in[5];
  const float* wo   = (const float*)d_in[6];
  const float* ln1g = (const float*)d_in[7];
  const float* ln1b = (const float*)d_in[8];
  const float* ln2g = (const float*)d_in[9];
  const float* ln2b = (const float*)d_in[10];
  const float* w1   = (const float*)d_in[11];
  const float* w2   = (const float*)d_in[12];
  const float* lnfg = (const float*)d_in[13];
  const float* lnfb = (const float*)d_in[14];
  float* out = (float*)d_out;

  // workspace layout (floats):
  // x: 2MB | q,k,v: 2MB each | pacc: 33.5MB | pl: 4MB  -> ~45.5MB total
  float* x    = (float*)d_ws;
  float* q    = x + (long)BT * Cc;
  float* k    = q + (long)Bc * Hc * Tc * HSc;
  float* v    = k + (long)Bc * Hc * Tc * HSc;
  float* pacc = v + (long)Bc * Hc * Tc * HSc;
  float* pl   = pacc + (long)Bc * Hc * NCH * Tc * HSc;

  dim3 agrid(Bc * Hc, NCH, NQB);

  embed_ln_qkv_kernel<<<BT / 64, 256, 0, stream>>>(
      idx, tok, pos, wq, wk, wv, ln1g, ln1b, x, q, k, v);
  attn_kernel<<<agrid, 256, 0, stream>>>(q, k, v, pacc, pl);
  red_mid_kernel<<<BT / 64, 256, 0, stream>>>(
      pacc, pl, wo, ln2g, ln2b, w1, w2,
      wq + Hc * Cc * HSc, wk + Hc * Cc * HSc, wv + Hc * Cc * HSc,
      ln1g + Cc, ln1b + Cc, x, q, k, v);
  attn_kernel<<<agrid, 256, 0, stream>>>(q, k, v, pacc, pl);
  red_lnf_head_kernel<<<BT / 64, 256, 0, stream>>>(
      pacc, pl, wo + Cc * Cc, ln2g + Cc, ln2b + Cc,
      w1 + 4 * Cc * Cc, w2 + 4 * Cc * Cc, lnfg, lnfb, x, tok, out);
}